// Round 7
// baseline (969.657 us; speedup 1.0000x reference)
//
#include <hip/hip_runtime.h>
#include <hip/hip_bf16.h>

constexpr int N_ENT = 50000;
constexpr int D     = 200;
constexpr int NE    = 200000;
constexpr int BATCH = 1024;
constexpr int NF    = 96;
constexpr int FLAT  = 18816;   // 96*14*14
constexpr int KP    = 224;     // K=200 padded to 7*32
constexpr float EPS = 1e-5f;

#define DEV static __device__ __forceinline__

typedef __attribute__((ext_vector_type(8))) __bf16 bf16x8;
typedef __attribute__((ext_vector_type(4))) float  f32x4;

DEV float bf2f(unsigned short u){ return __uint_as_float(((unsigned)u) << 16); }
DEV unsigned short f2bf(float f){
    unsigned u = __float_as_uint(f);
    return (unsigned short)((u + 0x7FFF + ((u >> 16) & 1)) >> 16);  // RNE
}
DEV float sigmoidf(float x){ return 1.f / (1.f + __expf(-x)); }
DEV bf16x8 bzero8(){ bf16x8 v; 
    #pragma unroll
    for (int i = 0; i < 8; ++i) v[i] = (__bf16)0.f; 
    return v; }

// ---------------------------------------------------------------------------
// pack B for zh-GEMM: wb[col][k] (col<800: basis[b][k][o], o=col>>2,b=col&3;
// 800..999: root[k][col-800]; else 0). [1008][224] bf16
__global__ __launch_bounds__(256) void k_pack_wb(const float* __restrict__ basis,
                                                 const float* __restrict__ root,
                                                 unsigned short* __restrict__ wb){
    int idx = blockIdx.x * 256 + threadIdx.x;
    if (idx >= 1008 * KP) return;
    int col = idx / KP, k = idx % KP;
    float v = 0.f;
    if (k < 200){
        if (col < 800){ int o = col >> 2, b = col & 3; v = basis[b * (D*D) + k * D + o]; }
        else if (col < 1000) v = root[k * D + (col - 800)];
    }
    wb[idx] = f2bf(v);
}

// gather+convert A for zh-GEMM: eb[m][k] = bf16(ent_emb[entity[m]][k]), padded
__global__ __launch_bounds__(256) void k_prep_eb(const float* __restrict__ ent_emb,
                                                 const int* __restrict__ entity,
                                                 unsigned short* __restrict__ eb){
    int gid = blockIdx.x * 256 + threadIdx.x;       // one per 8 elems
    int m = gid / 28, k0 = (gid % 28) * 8;
    if (m >= 50048) return;
    unsigned short o[8];
    if (m < N_ENT){
        long base = (long)entity[m] * D;
        #pragma unroll
        for (int j = 0; j < 8; ++j){
            int k = k0 + j;
            o[j] = (k < D) ? f2bf(ent_emb[base + k]) : 0;
        }
    } else {
        #pragma unroll
        for (int j = 0; j < 8; ++j) o[j] = 0;
    }
    *(ushort4*)(eb + (long)m * KP + k0)     = make_ushort4(o[0], o[1], o[2], o[3]);
    *(ushort4*)(eb + (long)m * KP + k0 + 4) = make_ushort4(o[4], o[5], o[6], o[7]);
}

// ---------------------------------------------------------------------------
// MFMA GEMM: [50048 x 224] @ [224 x 1008] -> z bf16 (col<800) / h fp32 (+gbias)
__global__ __launch_bounds__(256) void k_gemm_zh_mfma(const unsigned short* __restrict__ eb,
                                                      const unsigned short* __restrict__ wb,
                                                      const float* __restrict__ gbias,
                                                      unsigned short* __restrict__ z,
                                                      float* __restrict__ h){
    const int tid = threadIdx.x, w = tid >> 6, l = tid & 63;
    const int wm = w >> 1, wn = w & 1;
    const int m0 = blockIdx.y * 64 + wm * 32;
    const int n0 = blockIdx.x * 128 + wn * 64;
    const int lr = l & 15, lk = (l >> 4) * 8;
    f32x4 acc[2][4];
    #pragma unroll
    for (int mi = 0; mi < 2; ++mi)
        #pragma unroll
        for (int nj = 0; nj < 4; ++nj) acc[mi][nj] = (f32x4){0.f, 0.f, 0.f, 0.f};
    for (int k0 = 0; k0 < KP; k0 += 32){
        bf16x8 a[2], b[4];
        #pragma unroll
        for (int mi = 0; mi < 2; ++mi)
            a[mi] = *(const bf16x8*)(eb + (long)(m0 + mi*16 + lr) * KP + k0 + lk);
        #pragma unroll
        for (int nj = 0; nj < 4; ++nj){
            int col = n0 + nj*16 + lr;
            b[nj] = (col < 1008) ? *(const bf16x8*)(wb + (long)col * KP + k0 + lk) : bzero8();
        }
        #pragma unroll
        for (int mi = 0; mi < 2; ++mi)
            #pragma unroll
            for (int nj = 0; nj < 4; ++nj)
                acc[mi][nj] = __builtin_amdgcn_mfma_f32_16x16x32_bf16(a[mi], b[nj], acc[mi][nj], 0, 0, 0);
    }
    #pragma unroll
    for (int mi = 0; mi < 2; ++mi)
        #pragma unroll
        for (int r = 0; r < 4; ++r){
            int row = m0 + mi*16 + (l >> 4) * 4 + r;
            if (row >= N_ENT) continue;
            #pragma unroll
            for (int nj = 0; nj < 4; ++nj){
                int col = n0 + nj*16 + lr;
                float v = acc[mi][nj][r];
                if (col < 800)       z[(long)row * 800 + col] = f2bf(v);
                else if (col < 1000) h[row * D + (col - 800)] = v + gbias[col - 800];
            }
        }
}

// ---------------------------------------------------------------------------
// CSR build: count per-dst degree -> exclusive scan -> fill edge ids
__global__ __launch_bounds__(256) void k_deg(const int* __restrict__ edge_index,
                                             int* __restrict__ cnt){
    int e = blockIdx.x * 256 + threadIdx.x;
    if (e < NE) atomicAdd(&cnt[edge_index[NE + e]], 1);
}

// single-block exclusive scan over cnt[50000] -> rowptr[50001]; resets cnt to 0
__global__ __launch_bounds__(256) void k_scan(int* __restrict__ cnt,
                                              int* __restrict__ rowptr){
    __shared__ int sums[256];
    const int t = threadIdx.x;
    const int CH = 196;                         // 256*196 = 50176 >= 50000
    int start = t * CH, end = min(start + CH, N_ENT);
    int s = 0;
    for (int i = start; i < end; ++i) s += cnt[i];
    sums[t] = s;
    __syncthreads();
    if (t == 0){
        int acc = 0;
        for (int i = 0; i < 256; ++i){ int v = sums[i]; sums[i] = acc; acc += v; }
        rowptr[N_ENT] = acc;
    }
    __syncthreads();
    int acc = sums[t];
    for (int i = start; i < end; ++i){
        int v = cnt[i];
        rowptr[i] = acc;
        acc += v;
        cnt[i] = 0;                             // reset for k_fill's cursor
    }
}

__global__ __launch_bounds__(256) void k_fill(const int* __restrict__ edge_index,
                                              const int* __restrict__ rowptr,
                                              int* __restrict__ cnt,
                                              int* __restrict__ eidx){
    int e = blockIdx.x * 256 + threadIdx.x;
    if (e >= NE) return;
    int dst = edge_index[NE + e];
    int pos = rowptr[dst] + atomicAdd(&cnt[dst], 1);
    eidx[pos] = e;
}

// gather: one wave per dst node; h[dst] += sum_{e in(dst)} sum_b att[r,b]*norm * Z_b[src]
__global__ __launch_bounds__(256) void k_edge_gather(const unsigned short* __restrict__ z,
                                                     float* __restrict__ h,
                                                     const int* __restrict__ edge_index,
                                                     const int* __restrict__ edge_type,
                                                     const float* __restrict__ edge_norm,
                                                     const float* __restrict__ att,
                                                     const int* __restrict__ rowptr,
                                                     const int* __restrict__ eidx){
    int gw = (blockIdx.x * 256 + threadIdx.x) >> 6;
    int lane = threadIdx.x & 63;
    if (gw >= N_ENT) return;
    int beg = rowptr[gw], end = rowptr[gw + 1];
    if (beg == end) return;
    float acc[4] = {0.f, 0.f, 0.f, 0.f};
    for (int i = beg; i < end; ++i){
        int e = eidx[i];
        int src = edge_index[e];
        int r = edge_type[e];
        float nrm = edge_norm[e];
        float4 a = *(const float4*)(att + r * 4);
        float w0 = a.x * nrm, w1 = a.y * nrm, w2 = a.z * nrm, w3 = a.w * nrm;
        const unsigned short* zr = z + (long)src * 800;
        #pragma unroll
        for (int s = 0; s < 4; ++s){
            int d = lane + s * 64;
            if (d < D){
                ushort4 u = *(const ushort4*)(zr + d * 4);
                acc[s] += w0*bf2f(u.x) + w1*bf2f(u.y) + w2*bf2f(u.z) + w3*bf2f(u.w);
            }
        }
    }
    #pragma unroll
    for (int s = 0; s < 4; ++s){
        int d = lane + s * 64;
        if (d < D) h[gw * D + d] += acc[s];     // sole writer: no atomic
    }
}

// ---------------------------------------------------------------------------
DEV void block_reduce2(float& s, float& ss, float* red){
    #pragma unroll
    for (int o = 32; o > 0; o >>= 1){ s += __shfl_down(s, o); ss += __shfl_down(ss, o); }
    int w = threadIdx.x >> 6;
    if ((threadIdx.x & 63) == 0){ red[w*2] = s; red[w*2+1] = ss; }
    __syncthreads();
    if (threadIdx.x == 0){
        #pragma unroll
        for (int i = 1; i < 4; ++i){ s += red[i*2]; ss += red[i*2+1]; }
    }
}

__global__ __launch_bounds__(256) void k_bn0_stats(const float* __restrict__ h,
                                                   const float* __restrict__ rel_table,
                                                   const int* __restrict__ srcb,
                                                   const int* __restrict__ relb,
                                                   float* __restrict__ stats){
    __shared__ float red[8];
    int b = blockIdx.x;
    int sb = srcb[b], rb = relb[b];
    float s = 0.f, ss = 0.f;
    for (int idx = threadIdx.x; idx < 2*D; idx += 256){
        float v = (idx < D) ? h[sb*D + idx] : rel_table[rb*D + (idx - D)];
        s += v; ss += v * v;
    }
    block_reduce2(s, ss, red);
    if (threadIdx.x == 0){ atomicAdd(&stats[0], s); atomicAdd(&stats[1], ss); }
}

// h fp32 -> hb bf16 [50048][224] (B operand for logits)
__global__ __launch_bounds__(256) void k_h2bf(const float* __restrict__ h,
                                              unsigned short* __restrict__ hb){
    int gid = blockIdx.x * 256 + threadIdx.x;
    int m = gid / 28, k0 = (gid % 28) * 8;
    if (m >= 50048) return;
    unsigned short o[8];
    #pragma unroll
    for (int j = 0; j < 8; ++j){
        int k = k0 + j;
        o[j] = (m < N_ENT && k < D) ? f2bf(h[m*D + k]) : 0;
    }
    *(ushort4*)(hb + (long)m*KP + k0)     = make_ushort4(o[0], o[1], o[2], o[3]);
    *(ushort4*)(hb + (long)m*KP + k0 + 4) = make_ushort4(o[4], o[5], o[6], o[7]);
}

// fc_W [18816][200] fp32 -> fcwt [208][18816] bf16 (rows 200..207 zero), k = f*196+p order
__global__ __launch_bounds__(256) void k_pack_fcw(const float* __restrict__ fc_W,
                                                  unsigned short* __restrict__ fcwt){
    __shared__ float t[32][33];
    int k0 = blockIdx.x * 32, n0 = blockIdx.y * 32;
    int tx = threadIdx.x & 31, ty = threadIdx.x >> 5;   // 32 x 8
    #pragma unroll
    for (int i = 0; i < 4; ++i){
        int k = k0 + ty + i*8, n = n0 + tx;
        t[ty + i*8][tx] = (n < D) ? fc_W[(long)k * D + n] : 0.f;
    }
    __syncthreads();
    #pragma unroll
    for (int i = 0; i < 4; ++i){
        int n = n0 + ty + i*8, k = k0 + tx;
        if (n < 208) fcwt[(long)n * FLAT + k] = f2bf(t[tx][ty + i*8]);
    }
}

// conv kernel pack: ckb[f][k] (k<49: conv_k[f*49+k]; k==49: conv_b[f]; else 0), [96][64]
__global__ __launch_bounds__(256) void k_pack_ckb(const float* __restrict__ conv_k,
                                                  const float* __restrict__ conv_b,
                                                  unsigned short* __restrict__ ckb){
    for (int idx = threadIdx.x; idx < NF * 64; idx += 256){
        int f = idx >> 6, k = idx & 63;
        float v = (k < 49) ? conv_k[f * 49 + k] : (k == 49 ? conv_b[f] : 0.f);
        ckb[idx] = f2bf(v);
    }
}

// ---------------------------------------------------------------------------
// im2col: per batch, build bn0-normalized 20x20 image and emit A[(b,p)][64] bf16
__global__ __launch_bounds__(256) void k_im2col(const float* __restrict__ h,
                                               const float* __restrict__ rel_table,
                                               const int* __restrict__ srcb,
                                               const int* __restrict__ relb,
                                               const float* __restrict__ stats,
                                               const float* __restrict__ bn0_g,
                                               const float* __restrict__ bn0_b,
                                               unsigned short* __restrict__ A){
    __shared__ float img[20][21];   // +1 pad
    int b = blockIdx.x;
    float m0 = stats[0] * (1.f / 409600.f);
    float v0 = stats[1] * (1.f / 409600.f) - m0 * m0;
    float sc = rsqrtf(v0 + EPS) * bn0_g[0];
    float sh = bn0_b[0] - m0 * sc;
    int sb = srcb[b], rb = relb[b];
    for (int idx = threadIdx.x; idx < 400; idx += 256){
        int d = idx >> 1, c = idx & 1;           // image linear = d*2+c, row-major 20x20
        float v = c ? rel_table[rb*D + d] : h[sb*D + d];
        img[idx / 20][idx % 20] = v * sc + sh;
    }
    __syncthreads();
    for (int idx = threadIdx.x; idx < 196 * 8; idx += 256){
        int p = idx >> 3, g = idx & 7;
        int oy = p / 14, ox = p % 14, k0 = g * 8;
        unsigned short o[8];
        #pragma unroll
        for (int j = 0; j < 8; ++j){
            int k = k0 + j;
            float v = 0.f;
            if (k < 49){ int ky = k / 7, kx = k % 7; v = img[oy + ky][ox + kx]; }
            else if (k == 49) v = 1.f;
            o[j] = f2bf(v);
        }
        long base = ((long)b * 196 + p) * 64 + k0;
        *(ushort4*)(A + base)     = make_ushort4(o[0], o[1], o[2], o[3]);
        *(ushort4*)(A + base + 4) = make_ushort4(o[4], o[5], o[6], o[7]);
    }
}

// conv as MFMA GEMM: [200704 x 64] @ [64 x 96] -> conv_out[(b,p)][f] bf16
__global__ __launch_bounds__(256) void k_conv_mfma(const unsigned short* __restrict__ A,
                                                   const unsigned short* __restrict__ ckb,
                                                   unsigned short* __restrict__ conv_out){
    const int tid = threadIdx.x, w = tid >> 6, l = tid & 63;
    const int m0 = blockIdx.x * 128 + w * 32;
    const int lr = l & 15, lk = (l >> 4) * 8;
    f32x4 acc[2][6];
    #pragma unroll
    for (int mi = 0; mi < 2; ++mi)
        #pragma unroll
        for (int nj = 0; nj < 6; ++nj) acc[mi][nj] = (f32x4){0.f, 0.f, 0.f, 0.f};
    #pragma unroll
    for (int k0 = 0; k0 < 64; k0 += 32){
        bf16x8 a[2], b[6];
        #pragma unroll
        for (int mi = 0; mi < 2; ++mi)
            a[mi] = *(const bf16x8*)(A + (long)(m0 + mi*16 + lr) * 64 + k0 + lk);
        #pragma unroll
        for (int nj = 0; nj < 6; ++nj)
            b[nj] = *(const bf16x8*)(ckb + (nj*16 + lr) * 64 + k0 + lk);
        #pragma unroll
        for (int mi = 0; mi < 2; ++mi)
            #pragma unroll
            for (int nj = 0; nj < 6; ++nj)
                acc[mi][nj] = __builtin_amdgcn_mfma_f32_16x16x32_bf16(a[mi], b[nj], acc[mi][nj], 0, 0, 0);
    }
    #pragma unroll
    for (int mi = 0; mi < 2; ++mi)
        #pragma unroll
        for (int r = 0; r < 4; ++r){
            long row = m0 + mi*16 + (l >> 4) * 4 + r;
            #pragma unroll
            for (int nj = 0; nj < 6; ++nj)
                conv_out[row * 96 + nj*16 + lr] = f2bf(acc[mi][nj][r]);
        }
}

// bn1 stats over conv_out [200704][96]: column sums / sumsq per channel f
__global__ __launch_bounds__(256) void k_bn1_stats2(const unsigned short* __restrict__ conv_out,
                                                    float* __restrict__ s1sum,
                                                    float* __restrict__ s1ss){
    __shared__ float lsum[96], lss[96];
    int tid = threadIdx.x;
    if (tid < 96){ lsum[tid] = 0.f; lss[tid] = 0.f; }
    __syncthreads();
    if (tid < 192){
        int fg = tid % 24, rs = tid / 24;          // 24 col-groups x 8 row-slots
        long r0 = (long)blockIdx.x * 784;
        float s[4] = {}, ss[4] = {};
        for (int i = 0; i < 98; ++i){
            long r = r0 + rs + i * 8;
            ushort4 u = *(const ushort4*)(conv_out + r * 96 + fg * 4);
            float v0 = bf2f(u.x), v1 = bf2f(u.y), v2 = bf2f(u.z), v3 = bf2f(u.w);
            s[0] += v0; ss[0] += v0*v0; s[1] += v1; ss[1] += v1*v1;
            s[2] += v2; ss[2] += v2*v2; s[3] += v3; ss[3] += v3*v3;
        }
        #pragma unroll
        for (int j = 0; j < 4; ++j){
            atomicAdd(&lsum[fg*4 + j], s[j]);
            atomicAdd(&lss[fg*4 + j], ss[j]);
        }
    }
    __syncthreads();
    if (tid < 96){
        atomicAdd(&s1sum[tid], lsum[tid]);
        atomicAdd(&s1ss[tid], lss[tid]);
    }
}

__global__ __launch_bounds__(128) void k_bn1_final(const float* __restrict__ s1sum,
                                                   const float* __restrict__ s1ss,
                                                   const float* __restrict__ bn1_g,
                                                   const float* __restrict__ bn1_b,
                                                   float* __restrict__ scale1,
                                                   float* __restrict__ shift1){
    int c = threadIdx.x;
    if (c < NF){
        float m = s1sum[c] * (1.f / 200704.f);
        float var = s1ss[c] * (1.f / 200704.f) - m * m;
        float scv = rsqrtf(var + EPS) * bn1_g[c];
        scale1[c] = scv;
        shift1[c] = bn1_b[c] - m * scv;
    }
}

// apply bn1+relu and transpose per batch: conv_out[b][p][f] -> fcA[b][f*196+p]
__global__ __launch_bounds__(256) void k_bn1_tr(const unsigned short* __restrict__ conv_out,
                                                const float* __restrict__ scale1,
                                                const float* __restrict__ shift1,
                                                unsigned short* __restrict__ fcA){
    __shared__ unsigned short lds[FLAT];
    int b = blockIdx.x, tid = threadIdx.x;
    for (int idx = tid; idx < 2352; idx += 256){           // 8 elems each
        long base = (long)b * FLAT + idx * 8;
        ushort4 u0 = *(const ushort4*)(conv_out + base);
        ushort4 u1 = *(const ushort4*)(conv_out + base + 4);
        unsigned short in[8] = {u0.x,u0.y,u0.z,u0.w,u1.x,u1.y,u1.z,u1.w};
        unsigned short o[8];
        int f0 = (idx * 8) % 96;
        #pragma unroll
        for (int j = 0; j < 8; ++j){
            float v = bf2f(in[j]) * scale1[f0 + j] + shift1[f0 + j];
            o[j] = f2bf(fmaxf(v, 0.f));
        }
        *(ushort4*)(lds + idx*8)     = make_ushort4(o[0], o[1], o[2], o[3]);
        *(ushort4*)(lds + idx*8 + 4) = make_ushort4(o[4], o[5], o[6], o[7]);
    }
    __syncthreads();
    for (int idx = tid; idx < 4704; idx += 256){           // 4 elems each, q = idx*4
        int q = idx * 4;
        int f = q / 196, p0 = q % 196;
        unsigned short o[4];
        #pragma unroll
        for (int j = 0; j < 4; ++j) o[j] = lds[(p0 + j) * 96 + f];
        *(ushort4*)(fcA + (long)b * FLAT + q) = make_ushort4(o[0], o[1], o[2], o[3]);
    }
}

// ---------------------------------------------------------------------------
// fc MFMA: [1024 x 18816] @ [18816 x 208], K split 12-way, atomic fp32 accumulate
__global__ __launch_bounds__(256) void k_fc_mfma(const unsigned short* __restrict__ ab,
                                                 const unsigned short* __restrict__ fcwt,
                                                 float* __restrict__ fc_out){
    const int tid = threadIdx.x, w = tid >> 6, l = tid & 63;
    const int wm = w >> 1, wn = w & 1;
    const int m0 = blockIdx.y * 64 + wm * 32;
    const int n0 = blockIdx.x * 64 + wn * 32;
    const int kb = blockIdx.z * 1568;
    const int lr = l & 15, lk = (l >> 4) * 8;
    f32x4 acc[2][2];
    #pragma unroll
    for (int mi = 0; mi < 2; ++mi)
        #pragma unroll
        for (int nj = 0; nj < 2; ++nj) acc[mi][nj] = (f32x4){0.f, 0.f, 0.f, 0.f};
    for (int k0 = kb; k0 < kb + 1568; k0 += 32){
        bf16x8 a[2], b[2];
        #pragma unroll
        for (int mi = 0; mi < 2; ++mi)
            a[mi] = *(const bf16x8*)(ab + (long)(m0 + mi*16 + lr) * FLAT + k0 + lk);
        #pragma unroll
        for (int nj = 0; nj < 2; ++nj){
            int col = n0 + nj*16 + lr;
            b[nj] = (col < 208) ? *(const bf16x8*)(fcwt + (long)col * FLAT + k0 + lk) : bzero8();
        }
        #pragma unroll
        for (int mi = 0; mi < 2; ++mi)
            #pragma unroll
            for (int nj = 0; nj < 2; ++nj)
                acc[mi][nj] = __builtin_amdgcn_mfma_f32_16x16x32_bf16(a[mi], b[nj], acc[mi][nj], 0, 0, 0);
    }
    #pragma unroll
    for (int mi = 0; mi < 2; ++mi)
        #pragma unroll
        for (int r = 0; r < 4; ++r){
            int row = m0 + mi*16 + (l >> 4) * 4 + r;
            #pragma unroll
            for (int nj = 0; nj < 2; ++nj){
                int col = n0 + nj*16 + lr;
                if (col < 208) atomicAdd(&fc_out[row * 208 + col], acc[mi][nj][r]);
            }
        }
}

__global__ __launch_bounds__(256) void k_bn2_stats(const float* __restrict__ fc_out,
                                                   const float* __restrict__ bn2_g,
                                                   const float* __restrict__ bn2_b,
                                                   float* __restrict__ sc2,
                                                   float* __restrict__ sh2){
    __shared__ float red[8];
    int n = blockIdx.x;
    float s = 0.f, ss = 0.f;
    for (int b = threadIdx.x; b < BATCH; b += 256){
        float v = fc_out[b * 208 + n];
        s += v; ss += v * v;
    }
    block_reduce2(s, ss, red);
    if (threadIdx.x == 0){
        float m = s * (1.f / 1024.f);
        float var = ss * (1.f / 1024.f) - m * m;
        float scv = rsqrtf(var + EPS) * bn2_g[n];
        sc2[n] = scv;
        sh2[n] = bn2_b[n] - m * scv;
    }
}

// A for logits: ab_l[b][k] = bf16(relu(bn2(fc_out))), [1024][224]
__global__ __launch_bounds__(256) void k_prep_logitsA(const float* __restrict__ fc_out,
                                                      const float* __restrict__ sc2,
                                                      const float* __restrict__ sh2,
                                                      unsigned short* __restrict__ ab_l){
    int idx = blockIdx.x * 256 + threadIdx.x;
    if (idx >= BATCH * KP) return;
    int b = idx / KP, k = idx % KP;
    float v = 0.f;
    if (k < D) v = fmaxf(fc_out[b * 208 + k] * sc2[k] + sh2[k], 0.f);
    ab_l[idx] = f2bf(v);
}

// ---------------------------------------------------------------------------
// logits MFMA: [1024 x 224] @ [224 x 50048] -> sigmoid(. + ent_bias) fp32
__global__ __launch_bounds__(256) void k_logits_mfma(const unsigned short* __restrict__ ab_l,
                                                     const unsigned short* __restrict__ hb,
                                                     const float* __restrict__ ent_bias,
                                                     float* __restrict__ out){
    const int tid = threadIdx.x, w = tid >> 6, l = tid & 63;
    const int wm = w >> 1, wn = w & 1;
    const int m0 = blockIdx.y * 64 + wm * 32;
    const int n0 = blockIdx.x * 128 + wn * 64;
    const int lr = l & 15, lk = (l >> 4) * 8;
    f32x4 acc[2][4];
    #pragma unroll
    for (int mi = 0; mi < 2; ++mi)
        #pragma unroll
        for (int nj = 0; nj < 4; ++nj) acc[mi][nj] = (f32x4){0.f, 0.f, 0.f, 0.f};
    for (int k0 = 0; k0 < KP; k0 += 32){
        bf16x8 a[2], b[4];
        #pragma unroll
        for (int mi = 0; mi < 2; ++mi)
            a[mi] = *(const bf16x8*)(ab_l + (long)(m0 + mi*16 + lr) * KP + k0 + lk);
        #pragma unroll
        for (int nj = 0; nj < 4; ++nj){
            int cb = n0 + nj*16;
            b[nj] = (cb < N_ENT) ? *(const bf16x8*)(hb + (long)(cb + lr) * KP + k0 + lk) : bzero8();
        }
        #pragma unroll
        for (int mi = 0; mi < 2; ++mi)
            #pragma unroll
            for (int nj = 0; nj < 4; ++nj)
                acc[mi][nj] = __builtin_amdgcn_mfma_f32_16x16x32_bf16(a[mi], b[nj], acc[mi][nj], 0, 0, 0);
    }
    #pragma unroll
    for (int mi = 0; mi < 2; ++mi)
        #pragma unroll
        for (int r = 0; r < 4; ++r){
            int row = m0 + mi*16 + (l >> 4) * 4 + r;
            #pragma unroll
            for (int nj = 0; nj < 4; ++nj){
                int cb = n0 + nj*16;
                if (cb < N_ENT){
                    int col = cb + lr;
                    out[(long)row * N_ENT + col] = sigmoidf(acc[mi][nj][r] + ent_bias[col]);
                }
            }
        }
}

// ---------------------------------------------------------------------------
extern "C" void kernel_launch(void* const* d_in, const int* in_sizes, int n_in,
                              void* d_out, int out_size, void* d_ws, size_t ws_size,
                              hipStream_t stream){
    const float* ent_emb   = (const float*)d_in[0];
    const float* rel_table = (const float*)d_in[1];
    const float* basis     = (const float*)d_in[2];
    const float* att       = (const float*)d_in[3];
    const float* root      = (const float*)d_in[4];
    const float* gbias     = (const float*)d_in[5];
    const float* bn0_g     = (const float*)d_in[6];
    const float* bn0_b     = (const float*)d_in[7];
    const float* conv_k    = (const float*)d_in[8];
    const float* conv_b    = (const float*)d_in[9];
    const float* bn1_g     = (const float*)d_in[10];
    const float* bn1_b     = (const float*)d_in[11];
    const float* fc_W      = (const float*)d_in[12];
    // d_in[13] fc_b cancels through bn2's batch-mean subtraction
    const float* bn2_g     = (const float*)d_in[14];
    const float* bn2_b     = (const float*)d_in[15];
    const float* ent_bias  = (const float*)d_in[16];
    const float* edge_norm = (const float*)d_in[17];
    const int*   entity    = (const int*)d_in[18];
    const int*   edge_index= (const int*)d_in[19];
    const int*   edge_type = (const int*)d_in[20];
    const int*   srcb      = (const int*)d_in[21];
    const int*   relb      = (const int*)d_in[22];
    float* out = (float*)d_out;

    // workspace layout (~160.3 MB). z [0,80M) is dead after edge gather; within it:
    //   hb   [0, 22.42M)          (after edge)
    //   ckb  @22,500,096 (12 KB)  (after edge)
    //   imA  @24M (25.7M)         (after edge; dead after conv gemm)
    //   fcA  @24M (38.5M)         (aliases imA, written after conv gemm)
    //   fcwt @63M (7.8M)          (after edge)
    // CSR arrays alias eb's region [120M, ...): eb is dead after k_gemm_zh,
    // conv_out (also @120M) is written only after the gather completes.
    char* ws = (char*)d_ws;
    unsigned short* z        = (unsigned short*)(ws);
    unsigned short* hb       = (unsigned short*)(ws);
    unsigned short* ckb      = (unsigned short*)(ws + 22500096);
    unsigned short* imA      = (unsigned short*)(ws + 24000000);
    unsigned short* fcA      = (unsigned short*)(ws + 24000000);
    unsigned short* fcwt     = (unsigned short*)(ws + 63000000);
    float*          h        = (float*)(ws + 80000000);               // 40,000,000 B
    unsigned short* conv_out = (unsigned short*)(ws + 120000000);     // 38,535,168 B
    unsigned short* eb       = (unsigned short*)(ws + 120000000);     // 22,421,504 B (early)
    int*            rowptr   = (int*)(ws + 120000000);                // 200,004 B (CSR phase)
    int*            cntc     = (int*)(ws + 120200192);                // 200,000 B
    int*            eidx     = (int*)(ws + 120400192);                // 800,000 B
    unsigned short* wb       = (unsigned short*)(ws + 158535168);     //    451,584 B
    float*          fc_out   = (float*)(ws + 158986752);              //    851,968 B
    unsigned short* ab_l     = (unsigned short*)(ws + 159838720);     //    458,752 B
    float*          stats    = (float*)(ws + 160297472);              //      4,096 B
    float* s1sum  = stats + 8;    // [96]
    float* s1ss   = stats + 104;  // [96]
    float* scale1 = stats + 200;  // [96]
    float* shift1 = stats + 296;  // [96]
    float* sc2    = stats + 392;  // [200]
    float* sh2    = stats + 592;  // [200]

    hipMemsetAsync(stats, 0, 4096, stream);
    hipMemsetAsync(fc_out, 0, BATCH * 208 * sizeof(float), stream);

    k_pack_wb      <<<(1008 * KP + 255) / 256, 256, 0, stream>>>(basis, root, wb);
    k_prep_eb      <<<(50048 * 28 + 255) / 256, 256, 0, stream>>>(ent_emb, entity, eb);
    k_gemm_zh_mfma <<<dim3(8, 782), 256, 0, stream>>>(eb, wb, gbias, z, h);
    // CSR build (aliases dead eb region) + gather (no atomics on h)
    hipMemsetAsync(cntc, 0, N_ENT * sizeof(int), stream);
    k_deg          <<<(NE + 255) / 256, 256, 0, stream>>>(edge_index, cntc);
    k_scan         <<<1, 256, 0, stream>>>(cntc, rowptr);
    k_fill         <<<(NE + 255) / 256, 256, 0, stream>>>(edge_index, rowptr, cntc, eidx);
    k_edge_gather  <<<(N_ENT * 64 + 255) / 256, 256, 0, stream>>>(z, h, edge_index,
                                                                  edge_type, edge_norm, att,
                                                                  rowptr, eidx);
    k_bn0_stats    <<<BATCH, 256, 0, stream>>>(h, rel_table, srcb, relb, stats);
    k_h2bf         <<<(50048 * 28 + 255) / 256, 256, 0, stream>>>(h, hb);
    k_pack_fcw     <<<dim3(588, 7), 256, 0, stream>>>(fc_W, fcwt);
    k_pack_ckb     <<<1, 256, 0, stream>>>(conv_k, conv_b, ckb);
    k_im2col       <<<BATCH, 256, 0, stream>>>(h, rel_table, srcb, relb, stats,
                                               bn0_g, bn0_b, imA);
    k_conv_mfma    <<<1568, 256, 0, stream>>>(imA, ckb, conv_out);
    k_bn1_stats2   <<<256, 256, 0, stream>>>(conv_out, s1sum, s1ss);
    k_bn1_final    <<<1, 128, 0, stream>>>(s1sum, s1ss, bn1_g, bn1_b, scale1, shift1);
    k_bn1_tr       <<<BATCH, 256, 0, stream>>>(conv_out, scale1, shift1, fcA);
    k_fc_mfma      <<<dim3(4, 16, 12), 256, 0, stream>>>(fcA, fcwt, fc_out);
    k_bn2_stats    <<<D, 256, 0, stream>>>(fc_out, bn2_g, bn2_b, sc2, sh2);
    k_prep_logitsA <<<(BATCH * KP + 255) / 256, 256, 0, stream>>>(fc_out, sc2, sh2, ab_l);
    k_logits_mfma  <<<dim3(391, 16), 256, 0, stream>>>(ab_l, hb, ent_bias, out);
}

// Round 8
// 899.377 us; speedup vs baseline: 1.0781x; 1.0781x over previous
//
#include <hip/hip_runtime.h>
#include <hip/hip_bf16.h>

constexpr int N_ENT = 50000;
constexpr int D     = 200;
constexpr int NE    = 200000;
constexpr int BATCH = 1024;
constexpr int NF    = 96;
constexpr int FLAT  = 18816;   // 96*14*14
constexpr int KP    = 224;     // K=200 padded to 7*32
constexpr float EPS = 1e-5f;

#define DEV static __device__ __forceinline__

typedef __attribute__((ext_vector_type(8))) __bf16 bf16x8;
typedef __attribute__((ext_vector_type(4))) float  f32x4;

DEV float bf2f(unsigned short u){ return __uint_as_float(((unsigned)u) << 16); }
DEV unsigned short f2bf(float f){
    unsigned u = __float_as_uint(f);
    return (unsigned short)((u + 0x7FFF + ((u >> 16) & 1)) >> 16);  // RNE
}
DEV float sigmoidf(float x){ return 1.f / (1.f + __expf(-x)); }
DEV bf16x8 bzero8(){ bf16x8 v; 
    #pragma unroll
    for (int i = 0; i < 8; ++i) v[i] = (__bf16)0.f; 
    return v; }

// ---------------------------------------------------------------------------
// pack B for zh-GEMM: wb[col][k] (col<800: basis[b][k][o], o=col>>2,b=col&3;
// 800..999: root[k][col-800]; else 0). [1008][224] bf16
__global__ __launch_bounds__(256) void k_pack_wb(const float* __restrict__ basis,
                                                 const float* __restrict__ root,
                                                 unsigned short* __restrict__ wb){
    int idx = blockIdx.x * 256 + threadIdx.x;
    if (idx >= 1008 * KP) return;
    int col = idx / KP, k = idx % KP;
    float v = 0.f;
    if (k < 200){
        if (col < 800){ int o = col >> 2, b = col & 3; v = basis[b * (D*D) + k * D + o]; }
        else if (col < 1000) v = root[k * D + (col - 800)];
    }
    wb[idx] = f2bf(v);
}

// gather+convert A for zh-GEMM: eb[m][k] = bf16(ent_emb[entity[m]][k]), padded
__global__ __launch_bounds__(256) void k_prep_eb(const float* __restrict__ ent_emb,
                                                 const int* __restrict__ entity,
                                                 unsigned short* __restrict__ eb){
    int gid = blockIdx.x * 256 + threadIdx.x;       // one per 8 elems
    int m = gid / 28, k0 = (gid % 28) * 8;
    if (m >= 50048) return;
    unsigned short o[8];
    if (m < N_ENT){
        long base = (long)entity[m] * D;
        #pragma unroll
        for (int j = 0; j < 8; ++j){
            int k = k0 + j;
            o[j] = (k < D) ? f2bf(ent_emb[base + k]) : 0;
        }
    } else {
        #pragma unroll
        for (int j = 0; j < 8; ++j) o[j] = 0;
    }
    *(ushort4*)(eb + (long)m * KP + k0)     = make_ushort4(o[0], o[1], o[2], o[3]);
    *(ushort4*)(eb + (long)m * KP + k0 + 4) = make_ushort4(o[4], o[5], o[6], o[7]);
}

// ---------------------------------------------------------------------------
// MFMA GEMM: [50048 x 224] @ [224 x 1008] -> z bf16 (col<800) / h fp32 (+gbias)
__global__ __launch_bounds__(256) void k_gemm_zh_mfma(const unsigned short* __restrict__ eb,
                                                      const unsigned short* __restrict__ wb,
                                                      const float* __restrict__ gbias,
                                                      unsigned short* __restrict__ z,
                                                      float* __restrict__ h){
    const int tid = threadIdx.x, w = tid >> 6, l = tid & 63;
    const int wm = w >> 1, wn = w & 1;
    const int m0 = blockIdx.y * 64 + wm * 32;
    const int n0 = blockIdx.x * 128 + wn * 64;
    const int lr = l & 15, lk = (l >> 4) * 8;
    f32x4 acc[2][4];
    #pragma unroll
    for (int mi = 0; mi < 2; ++mi)
        #pragma unroll
        for (int nj = 0; nj < 4; ++nj) acc[mi][nj] = (f32x4){0.f, 0.f, 0.f, 0.f};
    for (int k0 = 0; k0 < KP; k0 += 32){
        bf16x8 a[2], b[4];
        #pragma unroll
        for (int mi = 0; mi < 2; ++mi)
            a[mi] = *(const bf16x8*)(eb + (long)(m0 + mi*16 + lr) * KP + k0 + lk);
        #pragma unroll
        for (int nj = 0; nj < 4; ++nj){
            int col = n0 + nj*16 + lr;
            b[nj] = (col < 1008) ? *(const bf16x8*)(wb + (long)col * KP + k0 + lk) : bzero8();
        }
        #pragma unroll
        for (int mi = 0; mi < 2; ++mi)
            #pragma unroll
            for (int nj = 0; nj < 4; ++nj)
                acc[mi][nj] = __builtin_amdgcn_mfma_f32_16x16x32_bf16(a[mi], b[nj], acc[mi][nj], 0, 0, 0);
    }
    #pragma unroll
    for (int mi = 0; mi < 2; ++mi)
        #pragma unroll
        for (int r = 0; r < 4; ++r){
            int row = m0 + mi*16 + (l >> 4) * 4 + r;
            if (row >= N_ENT) continue;
            #pragma unroll
            for (int nj = 0; nj < 4; ++nj){
                int col = n0 + nj*16 + lr;
                float v = acc[mi][nj][r];
                if (col < 800)       z[(long)row * 800 + col] = f2bf(v);
                else if (col < 1000) h[row * D + (col - 800)] = v + gbias[col - 800];
            }
        }
}

// ---------------------------------------------------------------------------
// edge scatter: h[dst] += sum_b att[r,b]*norm * Z_b[src]
__global__ __launch_bounds__(256) void k_edge(const unsigned short* __restrict__ z,
                                              float* __restrict__ h,
                                              const int* __restrict__ edge_index,
                                              const int* __restrict__ edge_type,
                                              const float* __restrict__ edge_norm,
                                              const float* __restrict__ att){
    int gtid = blockIdx.x * 256 + threadIdx.x;
    int wave = gtid >> 6, lane = gtid & 63;
    int nw = (gridDim.x * 256) >> 6;
    for (int e = wave; e < NE; e += nw){
        int src = edge_index[e];
        int dst = edge_index[NE + e];
        int r = edge_type[e];
        float nrm = edge_norm[e];
        float w0 = att[r*4+0]*nrm, w1 = att[r*4+1]*nrm, w2 = att[r*4+2]*nrm, w3 = att[r*4+3]*nrm;
        #pragma unroll
        for (int s = 0; s < 4; ++s){
            int d = lane + s * 64;
            if (d < D){
                ushort4 u = *(const ushort4*)(z + ((long)src * D + d) * 4);
                float v = w0*bf2f(u.x) + w1*bf2f(u.y) + w2*bf2f(u.z) + w3*bf2f(u.w);
                atomicAdd(h + dst * D + d, v);
            }
        }
    }
}

// ---------------------------------------------------------------------------
DEV void block_reduce2(float& s, float& ss, float* red){
    #pragma unroll
    for (int o = 32; o > 0; o >>= 1){ s += __shfl_down(s, o); ss += __shfl_down(ss, o); }
    int w = threadIdx.x >> 6;
    if ((threadIdx.x & 63) == 0){ red[w*2] = s; red[w*2+1] = ss; }
    __syncthreads();
    if (threadIdx.x == 0){
        #pragma unroll
        for (int i = 1; i < 4; ++i){ s += red[i*2]; ss += red[i*2+1]; }
    }
}

__global__ __launch_bounds__(256) void k_bn0_stats(const float* __restrict__ h,
                                                   const float* __restrict__ rel_table,
                                                   const int* __restrict__ srcb,
                                                   const int* __restrict__ relb,
                                                   float* __restrict__ stats){
    __shared__ float red[8];
    int b = blockIdx.x;
    int sb = srcb[b], rb = relb[b];
    float s = 0.f, ss = 0.f;
    for (int idx = threadIdx.x; idx < 2*D; idx += 256){
        float v = (idx < D) ? h[sb*D + idx] : rel_table[rb*D + (idx - D)];
        s += v; ss += v * v;
    }
    block_reduce2(s, ss, red);
    if (threadIdx.x == 0){ atomicAdd(&stats[0], s); atomicAdd(&stats[1], ss); }
}

// h fp32 -> hb bf16 [50048][224] (B operand for logits)
__global__ __launch_bounds__(256) void k_h2bf(const float* __restrict__ h,
                                              unsigned short* __restrict__ hb){
    int gid = blockIdx.x * 256 + threadIdx.x;
    int m = gid / 28, k0 = (gid % 28) * 8;
    if (m >= 50048) return;
    unsigned short o[8];
    #pragma unroll
    for (int j = 0; j < 8; ++j){
        int k = k0 + j;
        o[j] = (m < N_ENT && k < D) ? f2bf(h[m*D + k]) : 0;
    }
    *(ushort4*)(hb + (long)m*KP + k0)     = make_ushort4(o[0], o[1], o[2], o[3]);
    *(ushort4*)(hb + (long)m*KP + k0 + 4) = make_ushort4(o[4], o[5], o[6], o[7]);
}

// fc_W [18816][200] fp32 -> fcwt [208][18816] bf16 (rows 200..207 zero), k = f*196+p order
__global__ __launch_bounds__(256) void k_pack_fcw(const float* __restrict__ fc_W,
                                                  unsigned short* __restrict__ fcwt){
    __shared__ float t[32][33];
    int k0 = blockIdx.x * 32, n0 = blockIdx.y * 32;
    int tx = threadIdx.x & 31, ty = threadIdx.x >> 5;   // 32 x 8
    #pragma unroll
    for (int i = 0; i < 4; ++i){
        int k = k0 + ty + i*8, n = n0 + tx;
        t[ty + i*8][tx] = (n < D) ? fc_W[(long)k * D + n] : 0.f;
    }
    __syncthreads();
    #pragma unroll
    for (int i = 0; i < 4; ++i){
        int n = n0 + ty + i*8, k = k0 + tx;
        if (n < 208) fcwt[(long)n * FLAT + k] = f2bf(t[tx][ty + i*8]);
    }
}

// conv kernel pack: ckb[f][k] (k<49: conv_k[f*49+k]; k==49: conv_b[f]; else 0), [96][64]
__global__ __launch_bounds__(256) void k_pack_ckb(const float* __restrict__ conv_k,
                                                  const float* __restrict__ conv_b,
                                                  unsigned short* __restrict__ ckb){
    for (int idx = threadIdx.x; idx < NF * 64; idx += 256){
        int f = idx >> 6, k = idx & 63;
        float v = (k < 49) ? conv_k[f * 49 + k] : (k == 49 ? conv_b[f] : 0.f);
        ckb[idx] = f2bf(v);
    }
}

// ---------------------------------------------------------------------------
// im2col: per batch, build bn0-normalized 20x20 image and emit A[(b,p)][64] bf16
__global__ __launch_bounds__(256) void k_im2col(const float* __restrict__ h,
                                               const float* __restrict__ rel_table,
                                               const int* __restrict__ srcb,
                                               const int* __restrict__ relb,
                                               const float* __restrict__ stats,
                                               const float* __restrict__ bn0_g,
                                               const float* __restrict__ bn0_b,
                                               unsigned short* __restrict__ A){
    __shared__ float img[20][21];   // +1 pad
    int b = blockIdx.x;
    float m0 = stats[0] * (1.f / 409600.f);
    float v0 = stats[1] * (1.f / 409600.f) - m0 * m0;
    float sc = rsqrtf(v0 + EPS) * bn0_g[0];
    float sh = bn0_b[0] - m0 * sc;
    int sb = srcb[b], rb = relb[b];
    for (int idx = threadIdx.x; idx < 400; idx += 256){
        int d = idx >> 1, c = idx & 1;           // image linear = d*2+c, row-major 20x20
        float v = c ? rel_table[rb*D + d] : h[sb*D + d];
        img[idx / 20][idx % 20] = v * sc + sh;
    }
    __syncthreads();
    for (int idx = threadIdx.x; idx < 196 * 8; idx += 256){
        int p = idx >> 3, g = idx & 7;
        int oy = p / 14, ox = p % 14, k0 = g * 8;
        unsigned short o[8];
        #pragma unroll
        for (int j = 0; j < 8; ++j){
            int k = k0 + j;
            float v = 0.f;
            if (k < 49){ int ky = k / 7, kx = k % 7; v = img[oy + ky][ox + kx]; }
            else if (k == 49) v = 1.f;
            o[j] = f2bf(v);
        }
        long base = ((long)b * 196 + p) * 64 + k0;
        *(ushort4*)(A + base)     = make_ushort4(o[0], o[1], o[2], o[3]);
        *(ushort4*)(A + base + 4) = make_ushort4(o[4], o[5], o[6], o[7]);
    }
}

// conv as MFMA GEMM: [200704 x 64] @ [64 x 96] -> conv_out[(b,p)][f] bf16
__global__ __launch_bounds__(256) void k_conv_mfma(const unsigned short* __restrict__ A,
                                                   const unsigned short* __restrict__ ckb,
                                                   unsigned short* __restrict__ conv_out){
    const int tid = threadIdx.x, w = tid >> 6, l = tid & 63;
    const int m0 = blockIdx.x * 128 + w * 32;
    const int lr = l & 15, lk = (l >> 4) * 8;
    f32x4 acc[2][6];
    #pragma unroll
    for (int mi = 0; mi < 2; ++mi)
        #pragma unroll
        for (int nj = 0; nj < 6; ++nj) acc[mi][nj] = (f32x4){0.f, 0.f, 0.f, 0.f};
    #pragma unroll
    for (int k0 = 0; k0 < 64; k0 += 32){
        bf16x8 a[2], b[6];
        #pragma unroll
        for (int mi = 0; mi < 2; ++mi)
            a[mi] = *(const bf16x8*)(A + (long)(m0 + mi*16 + lr) * 64 + k0 + lk);
        #pragma unroll
        for (int nj = 0; nj < 6; ++nj)
            b[nj] = *(const bf16x8*)(ckb + (nj*16 + lr) * 64 + k0 + lk);
        #pragma unroll
        for (int mi = 0; mi < 2; ++mi)
            #pragma unroll
            for (int nj = 0; nj < 6; ++nj)
                acc[mi][nj] = __builtin_amdgcn_mfma_f32_16x16x32_bf16(a[mi], b[nj], acc[mi][nj], 0, 0, 0);
    }
    #pragma unroll
    for (int mi = 0; mi < 2; ++mi)
        #pragma unroll
        for (int r = 0; r < 4; ++r){
            long row = m0 + mi*16 + (l >> 4) * 4 + r;
            #pragma unroll
            for (int nj = 0; nj < 6; ++nj)
                conv_out[row * 96 + nj*16 + lr] = f2bf(acc[mi][nj][r]);
        }
}

// bn1 stats over conv_out [200704][96]: column sums / sumsq per channel f
__global__ __launch_bounds__(256) void k_bn1_stats2(const unsigned short* __restrict__ conv_out,
                                                    float* __restrict__ s1sum,
                                                    float* __restrict__ s1ss){
    __shared__ float lsum[96], lss[96];
    int tid = threadIdx.x;
    if (tid < 96){ lsum[tid] = 0.f; lss[tid] = 0.f; }
    __syncthreads();
    if (tid < 192){
        int fg = tid % 24, rs = tid / 24;          // 24 col-groups x 8 row-slots
        long r0 = (long)blockIdx.x * 784;
        float s[4] = {}, ss[4] = {};
        for (int i = 0; i < 98; ++i){
            long r = r0 + rs + i * 8;
            ushort4 u = *(const ushort4*)(conv_out + r * 96 + fg * 4);
            float v0 = bf2f(u.x), v1 = bf2f(u.y), v2 = bf2f(u.z), v3 = bf2f(u.w);
            s[0] += v0; ss[0] += v0*v0; s[1] += v1; ss[1] += v1*v1;
            s[2] += v2; ss[2] += v2*v2; s[3] += v3; ss[3] += v3*v3;
        }
        #pragma unroll
        for (int j = 0; j < 4; ++j){
            atomicAdd(&lsum[fg*4 + j], s[j]);
            atomicAdd(&lss[fg*4 + j], ss[j]);
        }
    }
    __syncthreads();
    if (tid < 96){
        atomicAdd(&s1sum[tid], lsum[tid]);
        atomicAdd(&s1ss[tid], lss[tid]);
    }
}

__global__ __launch_bounds__(128) void k_bn1_final(const float* __restrict__ s1sum,
                                                   const float* __restrict__ s1ss,
                                                   const float* __restrict__ bn1_g,
                                                   const float* __restrict__ bn1_b,
                                                   float* __restrict__ scale1,
                                                   float* __restrict__ shift1){
    int c = threadIdx.x;
    if (c < NF){
        float m = s1sum[c] * (1.f / 200704.f);
        float var = s1ss[c] * (1.f / 200704.f) - m * m;
        float scv = rsqrtf(var + EPS) * bn1_g[c];
        scale1[c] = scv;
        shift1[c] = bn1_b[c] - m * scv;
    }
}

// apply bn1+relu and transpose per batch: conv_out[b][p][f] -> fcA[b][f*196+p]
__global__ __launch_bounds__(256) void k_bn1_tr(const unsigned short* __restrict__ conv_out,
                                                const float* __restrict__ scale1,
                                                const float* __restrict__ shift1,
                                                unsigned short* __restrict__ fcA){
    __shared__ unsigned short lds[FLAT];
    int b = blockIdx.x, tid = threadIdx.x;
    for (int idx = tid; idx < 2352; idx += 256){           // 8 elems each
        long base = (long)b * FLAT + idx * 8;
        ushort4 u0 = *(const ushort4*)(conv_out + base);
        ushort4 u1 = *(const ushort4*)(conv_out + base + 4);
        unsigned short in[8] = {u0.x,u0.y,u0.z,u0.w,u1.x,u1.y,u1.z,u1.w};
        unsigned short o[8];
        int f0 = (idx * 8) % 96;
        #pragma unroll
        for (int j = 0; j < 8; ++j){
            float v = bf2f(in[j]) * scale1[f0 + j] + shift1[f0 + j];
            o[j] = f2bf(fmaxf(v, 0.f));
        }
        *(ushort4*)(lds + idx*8)     = make_ushort4(o[0], o[1], o[2], o[3]);
        *(ushort4*)(lds + idx*8 + 4) = make_ushort4(o[4], o[5], o[6], o[7]);
    }
    __syncthreads();
    for (int idx = tid; idx < 4704; idx += 256){           // 4 elems each, q = idx*4
        int q = idx * 4;
        int f = q / 196, p0 = q % 196;
        unsigned short o[4];
        #pragma unroll
        for (int j = 0; j < 4; ++j) o[j] = lds[(p0 + j) * 96 + f];
        *(ushort4*)(fcA + (long)b * FLAT + q) = make_ushort4(o[0], o[1], o[2], o[3]);
    }
}

// ---------------------------------------------------------------------------
// fc MFMA: [1024 x 18816] @ [18816 x 208], K split 12-way, atomic fp32 accumulate
__global__ __launch_bounds__(256) void k_fc_mfma(const unsigned short* __restrict__ ab,
                                                 const unsigned short* __restrict__ fcwt,
                                                 float* __restrict__ fc_out){
    const int tid = threadIdx.x, w = tid >> 6, l = tid & 63;
    const int wm = w >> 1, wn = w & 1;
    const int m0 = blockIdx.y * 64 + wm * 32;
    const int n0 = blockIdx.x * 64 + wn * 32;
    const int kb = blockIdx.z * 1568;
    const int lr = l & 15, lk = (l >> 4) * 8;
    f32x4 acc[2][2];
    #pragma unroll
    for (int mi = 0; mi < 2; ++mi)
        #pragma unroll
        for (int nj = 0; nj < 2; ++nj) acc[mi][nj] = (f32x4){0.f, 0.f, 0.f, 0.f};
    for (int k0 = kb; k0 < kb + 1568; k0 += 32){
        bf16x8 a[2], b[2];
        #pragma unroll
        for (int mi = 0; mi < 2; ++mi)
            a[mi] = *(const bf16x8*)(ab + (long)(m0 + mi*16 + lr) * FLAT + k0 + lk);
        #pragma unroll
        for (int nj = 0; nj < 2; ++nj){
            int col = n0 + nj*16 + lr;
            b[nj] = (col < 208) ? *(const bf16x8*)(fcwt + (long)col * FLAT + k0 + lk) : bzero8();
        }
        #pragma unroll
        for (int mi = 0; mi < 2; ++mi)
            #pragma unroll
            for (int nj = 0; nj < 2; ++nj)
                acc[mi][nj] = __builtin_amdgcn_mfma_f32_16x16x32_bf16(a[mi], b[nj], acc[mi][nj], 0, 0, 0);
    }
    #pragma unroll
    for (int mi = 0; mi < 2; ++mi)
        #pragma unroll
        for (int r = 0; r < 4; ++r){
            int row = m0 + mi*16 + (l >> 4) * 4 + r;
            #pragma unroll
            for (int nj = 0; nj < 2; ++nj){
                int col = n0 + nj*16 + lr;
                if (col < 208) atomicAdd(&fc_out[row * 208 + col], acc[mi][nj][r]);
            }
        }
}

__global__ __launch_bounds__(256) void k_bn2_stats(const float* __restrict__ fc_out,
                                                   const float* __restrict__ bn2_g,
                                                   const float* __restrict__ bn2_b,
                                                   float* __restrict__ sc2,
                                                   float* __restrict__ sh2){
    __shared__ float red[8];
    int n = blockIdx.x;
    float s = 0.f, ss = 0.f;
    for (int b = threadIdx.x; b < BATCH; b += 256){
        float v = fc_out[b * 208 + n];
        s += v; ss += v * v;
    }
    block_reduce2(s, ss, red);
    if (threadIdx.x == 0){
        float m = s * (1.f / 1024.f);
        float var = ss * (1.f / 1024.f) - m * m;
        float scv = rsqrtf(var + EPS) * bn2_g[n];
        sc2[n] = scv;
        sh2[n] = bn2_b[n] - m * scv;
    }
}

// A for logits: ab_l[b][k] = bf16(relu(bn2(fc_out))), [1024][224]
__global__ __launch_bounds__(256) void k_prep_logitsA(const float* __restrict__ fc_out,
                                                      const float* __restrict__ sc2,
                                                      const float* __restrict__ sh2,
                                                      unsigned short* __restrict__ ab_l){
    int idx = blockIdx.x * 256 + threadIdx.x;
    if (idx >= BATCH * KP) return;
    int b = idx / KP, k = idx % KP;
    float v = 0.f;
    if (k < D) v = fmaxf(fc_out[b * 208 + k] * sc2[k] + sh2[k], 0.f);
    ab_l[idx] = f2bf(v);
}

// ---------------------------------------------------------------------------
// logits MFMA: [1024 x 224] @ [224 x 50048] -> sigmoid(. + ent_bias) fp32
// Grid: (m fast, n slow) so the 16 m-tiles of one hb n-panel are temporally
// adjacent -> hb panel served from L2/L3 instead of HBM re-fetch per m-pass.
__global__ __launch_bounds__(256) void k_logits_mfma(const unsigned short* __restrict__ ab_l,
                                                     const unsigned short* __restrict__ hb,
                                                     const float* __restrict__ ent_bias,
                                                     float* __restrict__ out){
    const int tid = threadIdx.x, w = tid >> 6, l = tid & 63;
    const int wm = w >> 1, wn = w & 1;
    const int m0 = blockIdx.x * 64 + wm * 32;
    const int n0 = blockIdx.y * 128 + wn * 64;
    const int lr = l & 15, lk = (l >> 4) * 8;
    f32x4 acc[2][4];
    #pragma unroll
    for (int mi = 0; mi < 2; ++mi)
        #pragma unroll
        for (int nj = 0; nj < 4; ++nj) acc[mi][nj] = (f32x4){0.f, 0.f, 0.f, 0.f};
    for (int k0 = 0; k0 < KP; k0 += 32){
        bf16x8 a[2], b[4];
        #pragma unroll
        for (int mi = 0; mi < 2; ++mi)
            a[mi] = *(const bf16x8*)(ab_l + (long)(m0 + mi*16 + lr) * KP + k0 + lk);
        #pragma unroll
        for (int nj = 0; nj < 4; ++nj){
            int cb = n0 + nj*16;
            b[nj] = (cb < N_ENT) ? *(const bf16x8*)(hb + (long)(cb + lr) * KP + k0 + lk) : bzero8();
        }
        #pragma unroll
        for (int mi = 0; mi < 2; ++mi)
            #pragma unroll
            for (int nj = 0; nj < 4; ++nj)
                acc[mi][nj] = __builtin_amdgcn_mfma_f32_16x16x32_bf16(a[mi], b[nj], acc[mi][nj], 0, 0, 0);
    }
    #pragma unroll
    for (int mi = 0; mi < 2; ++mi)
        #pragma unroll
        for (int r = 0; r < 4; ++r){
            int row = m0 + mi*16 + (l >> 4) * 4 + r;
            #pragma unroll
            for (int nj = 0; nj < 4; ++nj){
                int cb = n0 + nj*16;
                if (cb < N_ENT){
                    int col = cb + lr;
                    out[(long)row * N_ENT + col] = sigmoidf(acc[mi][nj][r] + ent_bias[col]);
                }
            }
        }
}

// ---------------------------------------------------------------------------
extern "C" void kernel_launch(void* const* d_in, const int* in_sizes, int n_in,
                              void* d_out, int out_size, void* d_ws, size_t ws_size,
                              hipStream_t stream){
    const float* ent_emb   = (const float*)d_in[0];
    const float* rel_table = (const float*)d_in[1];
    const float* basis     = (const float*)d_in[2];
    const float* att       = (const float*)d_in[3];
    const float* root      = (const float*)d_in[4];
    const float* gbias     = (const float*)d_in[5];
    const float* bn0_g     = (const float*)d_in[6];
    const float* bn0_b     = (const float*)d_in[7];
    const float* conv_k    = (const float*)d_in[8];
    const float* conv_b    = (const float*)d_in[9];
    const float* bn1_g     = (const float*)d_in[10];
    const float* bn1_b     = (const float*)d_in[11];
    const float* fc_W      = (const float*)d_in[12];
    // d_in[13] fc_b cancels through bn2's batch-mean subtraction
    const float* bn2_g     = (const float*)d_in[14];
    const float* bn2_b     = (const float*)d_in[15];
    const float* ent_bias  = (const float*)d_in[16];
    const float* edge_norm = (const float*)d_in[17];
    const int*   entity    = (const int*)d_in[18];
    const int*   edge_index= (const int*)d_in[19];
    const int*   edge_type = (const int*)d_in[20];
    const int*   srcb      = (const int*)d_in[21];
    const int*   relb      = (const int*)d_in[22];
    float* out = (float*)d_out;

    // workspace layout (~160.3 MB). z [0,80M) is dead after k_edge; within it:
    //   hb   [0, 22.42M)          (after edge)
    //   ckb  @22,500,096 (12 KB)  (after edge)
    //   imA  @24M (25.7M)         (after edge; dead after conv gemm)
    //   fcA  @24M (38.5M)         (aliases imA, written after conv gemm)
    //   fcwt @63M (7.8M)          (after edge)
    char* ws = (char*)d_ws;
    unsigned short* z        = (unsigned short*)(ws);
    unsigned short* hb       = (unsigned short*)(ws);
    unsigned short* ckb      = (unsigned short*)(ws + 22500096);
    unsigned short* imA      = (unsigned short*)(ws + 24000000);
    unsigned short* fcA      = (unsigned short*)(ws + 24000000);
    unsigned short* fcwt     = (unsigned short*)(ws + 63000000);
    float*          h        = (float*)(ws + 80000000);               // 40,000,000 B
    unsigned short* conv_out = (unsigned short*)(ws + 120000000);     // 38,535,168 B
    unsigned short* eb       = (unsigned short*)(ws + 120000000);     // 22,421,504 B (early)
    unsigned short* wb       = (unsigned short*)(ws + 158535168);     //    451,584 B
    float*          fc_out   = (float*)(ws + 158986752);              //    851,968 B
    unsigned short* ab_l     = (unsigned short*)(ws + 159838720);     //    458,752 B
    float*          stats    = (float*)(ws + 160297472);              //      4,096 B
    float* s1sum  = stats + 8;    // [96]
    float* s1ss   = stats + 104;  // [96]
    float* scale1 = stats + 200;  // [96]
    float* shift1 = stats + 296;  // [96]
    float* sc2    = stats + 392;  // [200]
    float* sh2    = stats + 592;  // [200]

    hipMemsetAsync(stats, 0, 4096, stream);
    hipMemsetAsync(fc_out, 0, BATCH * 208 * sizeof(float), stream);

    k_pack_wb      <<<(1008 * KP + 255) / 256, 256, 0, stream>>>(basis, root, wb);
    k_prep_eb      <<<(50048 * 28 + 255) / 256, 256, 0, stream>>>(ent_emb, entity, eb);
    k_gemm_zh_mfma <<<dim3(8, 782), 256, 0, stream>>>(eb, wb, gbias, z, h);
    k_edge         <<<2048, 256, 0, stream>>>(z, h, edge_index, edge_type, edge_norm, att);
    k_bn0_stats    <<<BATCH, 256, 0, stream>>>(h, rel_table, srcb, relb, stats);
    k_h2bf         <<<(50048 * 28 + 255) / 256, 256, 0, stream>>>(h, hb);
    k_pack_fcw     <<<dim3(588, 7), 256, 0, stream>>>(fc_W, fcwt);
    k_pack_ckb     <<<1, 256, 0, stream>>>(conv_k, conv_b, ckb);
    k_im2col       <<<BATCH, 256, 0, stream>>>(h, rel_table, srcb, relb, stats,
                                               bn0_g, bn0_b, imA);
    k_conv_mfma    <<<1568, 256, 0, stream>>>(imA, ckb, conv_out);
    k_bn1_stats2   <<<256, 256, 0, stream>>>(conv_out, s1sum, s1ss);
    k_bn1_final    <<<1, 128, 0, stream>>>(s1sum, s1ss, bn1_g, bn1_b, scale1, shift1);
    k_bn1_tr       <<<BATCH, 256, 0, stream>>>(conv_out, scale1, shift1, fcA);
    k_fc_mfma      <<<dim3(4, 16, 12), 256, 0, stream>>>(fcA, fcwt, fc_out);
    k_bn2_stats    <<<D, 256, 0, stream>>>(fc_out, bn2_g, bn2_b, sc2, sh2);
    k_prep_logitsA <<<(BATCH * KP + 255) / 256, 256, 0, stream>>>(fc_out, sc2, sh2, ab_l);
    k_logits_mfma  <<<dim3(16, 391), 256, 0, stream>>>(ab_l, hb, ent_bias, out);
}

// Round 10
// 823.686 us; speedup vs baseline: 1.1772x; 1.0919x over previous
//
#include <hip/hip_runtime.h>
#include <hip/hip_bf16.h>

constexpr int N_ENT = 50000;
constexpr int D     = 200;
constexpr int NE    = 200000;
constexpr int BATCH = 1024;
constexpr int NF    = 96;
constexpr int FLAT  = 18816;   // 96*14*14
constexpr int KP    = 224;     // K=200 padded to 7*32
constexpr float EPS = 1e-5f;

#define DEV static __device__ __forceinline__

typedef __attribute__((ext_vector_type(8))) __bf16 bf16x8;
typedef __attribute__((ext_vector_type(4))) float  f32x4;

DEV float bf2f(unsigned short u){ return __uint_as_float(((unsigned)u) << 16); }
DEV unsigned short f2bf(float f){
    unsigned u = __float_as_uint(f);
    return (unsigned short)((u + 0x7FFF + ((u >> 16) & 1)) >> 16);  // RNE
}
DEV float sigmoidf(float x){ return 1.f / (1.f + __expf(-x)); }
DEV bf16x8 bzero8(){ bf16x8 v; 
    #pragma unroll
    for (int i = 0; i < 8; ++i) v[i] = (__bf16)0.f; 
    return v; }

// packed bf16x2 atomic add (no HIP overload in ROCm 7.2 -> inline asm)
DEV void atomic_pk_add_bf16(unsigned short* addr, unsigned int packed){
    asm volatile("global_atomic_pk_add_bf16 %0, %1, off"
                 :: "v"(addr), "v"(packed) : "memory");
}

// ---------------------------------------------------------------------------
// pack B for zh-GEMM: wb[col][k] (col<800: basis[b][k][o], o=col>>2,b=col&3;
// 800..999: root[k][col-800]; else 0). [1008][224] bf16
__global__ __launch_bounds__(256) void k_pack_wb(const float* __restrict__ basis,
                                                 const float* __restrict__ root,
                                                 unsigned short* __restrict__ wb){
    int idx = blockIdx.x * 256 + threadIdx.x;
    if (idx >= 1008 * KP) return;
    int col = idx / KP, k = idx % KP;
    float v = 0.f;
    if (k < 200){
        if (col < 800){ int o = col >> 2, b = col & 3; v = basis[b * (D*D) + k * D + o]; }
        else if (col < 1000) v = root[k * D + (col - 800)];
    }
    wb[idx] = f2bf(v);
}

// gather+convert A for zh-GEMM: eb[m][k] = bf16(ent_emb[entity[m]][k]), padded
__global__ __launch_bounds__(256) void k_prep_eb(const float* __restrict__ ent_emb,
                                                 const int* __restrict__ entity,
                                                 unsigned short* __restrict__ eb){
    int gid = blockIdx.x * 256 + threadIdx.x;       // one per 8 elems
    int m = gid / 28, k0 = (gid % 28) * 8;
    if (m >= 50048) return;
    unsigned short o[8];
    if (m < N_ENT){
        long base = (long)entity[m] * D;
        #pragma unroll
        for (int j = 0; j < 8; ++j){
            int k = k0 + j;
            o[j] = (k < D) ? f2bf(ent_emb[base + k]) : 0;
        }
    } else {
        #pragma unroll
        for (int j = 0; j < 8; ++j) o[j] = 0;
    }
    *(ushort4*)(eb + (long)m * KP + k0)     = make_ushort4(o[0], o[1], o[2], o[3]);
    *(ushort4*)(eb + (long)m * KP + k0 + 4) = make_ushort4(o[4], o[5], o[6], o[7]);
}

// ---------------------------------------------------------------------------
// MFMA GEMM: [50048 x 224] @ [224 x 1008] -> z bf16 (col<800) / h bf16 (+gbias)
__global__ __launch_bounds__(256) void k_gemm_zh_mfma(const unsigned short* __restrict__ eb,
                                                      const unsigned short* __restrict__ wb,
                                                      const float* __restrict__ gbias,
                                                      unsigned short* __restrict__ z,
                                                      unsigned short* __restrict__ h){
    const int tid = threadIdx.x, w = tid >> 6, l = tid & 63;
    const int wm = w >> 1, wn = w & 1;
    const int m0 = blockIdx.y * 64 + wm * 32;
    const int n0 = blockIdx.x * 128 + wn * 64;
    const int lr = l & 15, lk = (l >> 4) * 8;
    f32x4 acc[2][4];
    #pragma unroll
    for (int mi = 0; mi < 2; ++mi)
        #pragma unroll
        for (int nj = 0; nj < 4; ++nj) acc[mi][nj] = (f32x4){0.f, 0.f, 0.f, 0.f};
    for (int k0 = 0; k0 < KP; k0 += 32){
        bf16x8 a[2], b[4];
        #pragma unroll
        for (int mi = 0; mi < 2; ++mi)
            a[mi] = *(const bf16x8*)(eb + (long)(m0 + mi*16 + lr) * KP + k0 + lk);
        #pragma unroll
        for (int nj = 0; nj < 4; ++nj){
            int col = n0 + nj*16 + lr;
            b[nj] = (col < 1008) ? *(const bf16x8*)(wb + (long)col * KP + k0 + lk) : bzero8();
        }
        #pragma unroll
        for (int mi = 0; mi < 2; ++mi)
            #pragma unroll
            for (int nj = 0; nj < 4; ++nj)
                acc[mi][nj] = __builtin_amdgcn_mfma_f32_16x16x32_bf16(a[mi], b[nj], acc[mi][nj], 0, 0, 0);
    }
    #pragma unroll
    for (int mi = 0; mi < 2; ++mi)
        #pragma unroll
        for (int r = 0; r < 4; ++r){
            int row = m0 + mi*16 + (l >> 4) * 4 + r;
            if (row >= N_ENT) continue;
            #pragma unroll
            for (int nj = 0; nj < 4; ++nj){
                int col = n0 + nj*16 + lr;
                float v = acc[mi][nj][r];
                if (col < 800)       z[(long)row * 800 + col] = f2bf(v);
                else if (col < 1000) h[row * D + (col - 800)] = f2bf(v + gbias[col - 800]);
            }
        }
}

// ---------------------------------------------------------------------------
// edge scatter: h[dst] += sum_b att[r,b]*norm * Z_b[src], packed bf16x2 atomics.
// Lane l handles dim pairs p = l, l+64 (p<100): dims (2p, 2p+1) = z cols [8p,8p+8).
__global__ __launch_bounds__(256) void k_edge(const unsigned short* __restrict__ z,
                                              unsigned short* __restrict__ h,
                                              const int* __restrict__ edge_index,
                                              const int* __restrict__ edge_type,
                                              const float* __restrict__ edge_norm,
                                              const float* __restrict__ att){
    int gtid = blockIdx.x * 256 + threadIdx.x;
    int wave = gtid >> 6, lane = gtid & 63;
    int nw = (gridDim.x * 256) >> 6;
    for (int e = wave; e < NE; e += nw){
        int src = edge_index[e];
        int dst = edge_index[NE + e];
        int r = edge_type[e];
        float nrm = edge_norm[e];
        float w0 = att[r*4+0]*nrm, w1 = att[r*4+1]*nrm, w2 = att[r*4+2]*nrm, w3 = att[r*4+3]*nrm;
        #pragma unroll
        for (int s = 0; s < 2; ++s){
            int p = lane + s * 64;
            if (p < 100){
                const unsigned short* zr = z + (long)src * 800 + p * 8;
                ushort4 u0 = *(const ushort4*)(zr);
                ushort4 u1 = *(const ushort4*)(zr + 4);
                float m0 = w0*bf2f(u0.x) + w1*bf2f(u0.y) + w2*bf2f(u0.z) + w3*bf2f(u0.w);
                float m1 = w0*bf2f(u1.x) + w1*bf2f(u1.y) + w2*bf2f(u1.z) + w3*bf2f(u1.w);
                unsigned int packed = (unsigned)f2bf(m0) | ((unsigned)f2bf(m1) << 16);
                atomic_pk_add_bf16(h + dst * D + p * 2, packed);
            }
        }
    }
}

// ---------------------------------------------------------------------------
DEV void block_reduce2(float& s, float& ss, float* red){
    #pragma unroll
    for (int o = 32; o > 0; o >>= 1){ s += __shfl_down(s, o); ss += __shfl_down(ss, o); }
    int w = threadIdx.x >> 6;
    if ((threadIdx.x & 63) == 0){ red[w*2] = s; red[w*2+1] = ss; }
    __syncthreads();
    if (threadIdx.x == 0){
        #pragma unroll
        for (int i = 1; i < 4; ++i){ s += red[i*2]; ss += red[i*2+1]; }
    }
}

__global__ __launch_bounds__(256) void k_bn0_stats(const unsigned short* __restrict__ h,
                                                   const float* __restrict__ rel_table,
                                                   const int* __restrict__ srcb,
                                                   const int* __restrict__ relb,
                                                   float* __restrict__ stats){
    __shared__ float red[8];
    int b = blockIdx.x;
    int sb = srcb[b], rb = relb[b];
    float s = 0.f, ss = 0.f;
    for (int idx = threadIdx.x; idx < 2*D; idx += 256){
        float v = (idx < D) ? bf2f(h[sb*D + idx]) : rel_table[rb*D + (idx - D)];
        s += v; ss += v * v;
    }
    block_reduce2(s, ss, red);
    if (threadIdx.x == 0){ atomicAdd(&stats[0], s); atomicAdd(&stats[1], ss); }
}

// h bf16 [n][200] -> hb bf16 [50048][224] padded (B operand for logits)
__global__ __launch_bounds__(256) void k_h2bf(const unsigned short* __restrict__ h,
                                              unsigned short* __restrict__ hb){
    int gid = blockIdx.x * 256 + threadIdx.x;
    int m = gid / 28, k0 = (gid % 28) * 8;
    if (m >= 50048) return;
    unsigned short o[8];
    #pragma unroll
    for (int j = 0; j < 8; ++j){
        int k = k0 + j;
        o[j] = (m < N_ENT && k < D) ? h[m*D + k] : 0;
    }
    *(ushort4*)(hb + (long)m*KP + k0)     = make_ushort4(o[0], o[1], o[2], o[3]);
    *(ushort4*)(hb + (long)m*KP + k0 + 4) = make_ushort4(o[4], o[5], o[6], o[7]);
}

// fc_W [18816][200] fp32 -> fcwt [208][18816] bf16 (rows 200..207 zero), k = f*196+p order
__global__ __launch_bounds__(256) void k_pack_fcw(const float* __restrict__ fc_W,
                                                  unsigned short* __restrict__ fcwt){
    __shared__ float t[32][33];
    int k0 = blockIdx.x * 32, n0 = blockIdx.y * 32;
    int tx = threadIdx.x & 31, ty = threadIdx.x >> 5;   // 32 x 8
    #pragma unroll
    for (int i = 0; i < 4; ++i){
        int k = k0 + ty + i*8, n = n0 + tx;
        t[ty + i*8][tx] = (n < D) ? fc_W[(long)k * D + n] : 0.f;
    }
    __syncthreads();
    #pragma unroll
    for (int i = 0; i < 4; ++i){
        int n = n0 + ty + i*8, k = k0 + tx;
        if (n < 208) fcwt[(long)n * FLAT + k] = f2bf(t[tx][ty + i*8]);
    }
}

// conv kernel pack: ckb[f][k] (k<49: conv_k[f*49+k]; k==49: conv_b[f]; else 0), [96][64]
__global__ __launch_bounds__(256) void k_pack_ckb(const float* __restrict__ conv_k,
                                                  const float* __restrict__ conv_b,
                                                  unsigned short* __restrict__ ckb){
    for (int idx = threadIdx.x; idx < NF * 64; idx += 256){
        int f = idx >> 6, k = idx & 63;
        float v = (k < 49) ? conv_k[f * 49 + k] : (k == 49 ? conv_b[f] : 0.f);
        ckb[idx] = f2bf(v);
    }
}

// ---------------------------------------------------------------------------
// im2col: per batch, build bn0-normalized 20x20 image and emit A[(b,p)][64] bf16
__global__ __launch_bounds__(256) void k_im2col(const unsigned short* __restrict__ h,
                                               const float* __restrict__ rel_table,
                                               const int* __restrict__ srcb,
                                               const int* __restrict__ relb,
                                               const float* __restrict__ stats,
                                               const float* __restrict__ bn0_g,
                                               const float* __restrict__ bn0_b,
                                               unsigned short* __restrict__ A){
    __shared__ float img[20][21];   // +1 pad
    int b = blockIdx.x;
    float m0 = stats[0] * (1.f / 409600.f);
    float v0 = stats[1] * (1.f / 409600.f) - m0 * m0;
    float sc = rsqrtf(v0 + EPS) * bn0_g[0];
    float sh = bn0_b[0] - m0 * sc;
    int sb = srcb[b], rb = relb[b];
    for (int idx = threadIdx.x; idx < 400; idx += 256){
        int d = idx >> 1, c = idx & 1;           // image linear = d*2+c, row-major 20x20
        float v = c ? rel_table[rb*D + d] : bf2f(h[sb*D + d]);
        img[idx / 20][idx % 20] = v * sc + sh;
    }
    __syncthreads();
    for (int idx = threadIdx.x; idx < 196 * 8; idx += 256){
        int p = idx >> 3, g = idx & 7;
        int oy = p / 14, ox = p % 14, k0 = g * 8;
        unsigned short o[8];
        #pragma unroll
        for (int j = 0; j < 8; ++j){
            int k = k0 + j;
            float v = 0.f;
            if (k < 49){ int ky = k / 7, kx = k % 7; v = img[oy + ky][ox + kx]; }
            else if (k == 49) v = 1.f;
            o[j] = f2bf(v);
        }
        long base = ((long)b * 196 + p) * 64 + k0;
        *(ushort4*)(A + base)     = make_ushort4(o[0], o[1], o[2], o[3]);
        *(ushort4*)(A + base + 4) = make_ushort4(o[4], o[5], o[6], o[7]);
    }
}

// conv as MFMA GEMM: [200704 x 64] @ [64 x 96] -> conv_out[(b,p)][f] bf16
__global__ __launch_bounds__(256) void k_conv_mfma(const unsigned short* __restrict__ A,
                                                   const unsigned short* __restrict__ ckb,
                                                   unsigned short* __restrict__ conv_out){
    const int tid = threadIdx.x, w = tid >> 6, l = tid & 63;
    const int m0 = blockIdx.x * 128 + w * 32;
    const int lr = l & 15, lk = (l >> 4) * 8;
    f32x4 acc[2][6];
    #pragma unroll
    for (int mi = 0; mi < 2; ++mi)
        #pragma unroll
        for (int nj = 0; nj < 6; ++nj) acc[mi][nj] = (f32x4){0.f, 0.f, 0.f, 0.f};
    #pragma unroll
    for (int k0 = 0; k0 < 64; k0 += 32){
        bf16x8 a[2], b[6];
        #pragma unroll
        for (int mi = 0; mi < 2; ++mi)
            a[mi] = *(const bf16x8*)(A + (long)(m0 + mi*16 + lr) * 64 + k0 + lk);
        #pragma unroll
        for (int nj = 0; nj < 6; ++nj)
            b[nj] = *(const bf16x8*)(ckb + (nj*16 + lr) * 64 + k0 + lk);
        #pragma unroll
        for (int mi = 0; mi < 2; ++mi)
            #pragma unroll
            for (int nj = 0; nj < 6; ++nj)
                acc[mi][nj] = __builtin_amdgcn_mfma_f32_16x16x32_bf16(a[mi], b[nj], acc[mi][nj], 0, 0, 0);
    }
    #pragma unroll
    for (int mi = 0; mi < 2; ++mi)
        #pragma unroll
        for (int r = 0; r < 4; ++r){
            long row = m0 + mi*16 + (l >> 4) * 4 + r;
            #pragma unroll
            for (int nj = 0; nj < 6; ++nj)
                conv_out[row * 96 + nj*16 + lr] = f2bf(acc[mi][nj][r]);
        }
}

// bn1 stats over conv_out [200704][96]: column sums / sumsq per channel f
__global__ __launch_bounds__(256) void k_bn1_stats2(const unsigned short* __restrict__ conv_out,
                                                    float* __restrict__ s1sum,
                                                    float* __restrict__ s1ss){
    __shared__ float lsum[96], lss[96];
    int tid = threadIdx.x;
    if (tid < 96){ lsum[tid] = 0.f; lss[tid] = 0.f; }
    __syncthreads();
    if (tid < 192){
        int fg = tid % 24, rs = tid / 24;          // 24 col-groups x 8 row-slots
        long r0 = (long)blockIdx.x * 784;
        float s[4] = {}, ss[4] = {};
        for (int i = 0; i < 98; ++i){
            long r = r0 + rs + i * 8;
            ushort4 u = *(const ushort4*)(conv_out + r * 96 + fg * 4);
            float v0 = bf2f(u.x), v1 = bf2f(u.y), v2 = bf2f(u.z), v3 = bf2f(u.w);
            s[0] += v0; ss[0] += v0*v0; s[1] += v1; ss[1] += v1*v1;
            s[2] += v2; ss[2] += v2*v2; s[3] += v3; ss[3] += v3*v3;
        }
        #pragma unroll
        for (int j = 0; j < 4; ++j){
            atomicAdd(&lsum[fg*4 + j], s[j]);
            atomicAdd(&lss[fg*4 + j], ss[j]);
        }
    }
    __syncthreads();
    if (tid < 96){
        atomicAdd(&s1sum[tid], lsum[tid]);
        atomicAdd(&s1ss[tid], lss[tid]);
    }
}

__global__ __launch_bounds__(128) void k_bn1_final(const float* __restrict__ s1sum,
                                                   const float* __restrict__ s1ss,
                                                   const float* __restrict__ bn1_g,
                                                   const float* __restrict__ bn1_b,
                                                   float* __restrict__ scale1,
                                                   float* __restrict__ shift1){
    int c = threadIdx.x;
    if (c < NF){
        float m = s1sum[c] * (1.f / 200704.f);
        float var = s1ss[c] * (1.f / 200704.f) - m * m;
        float scv = rsqrtf(var + EPS) * bn1_g[c];
        scale1[c] = scv;
        shift1[c] = bn1_b[c] - m * scv;
    }
}

// apply bn1+relu and transpose per batch: conv_out[b][p][f] -> fcA[b][f*196+p]
__global__ __launch_bounds__(256) void k_bn1_tr(const unsigned short* __restrict__ conv_out,
                                                const float* __restrict__ scale1,
                                                const float* __restrict__ shift1,
                                                unsigned short* __restrict__ fcA){
    __shared__ unsigned short lds[FLAT];
    int b = blockIdx.x, tid = threadIdx.x;
    for (int idx = tid; idx < 2352; idx += 256){           // 8 elems each
        long base = (long)b * FLAT + idx * 8;
        ushort4 u0 = *(const ushort4*)(conv_out + base);
        ushort4 u1 = *(const ushort4*)(conv_out + base + 4);
        unsigned short in[8] = {u0.x,u0.y,u0.z,u0.w,u1.x,u1.y,u1.z,u1.w};
        unsigned short o[8];
        int f0 = (idx * 8) % 96;
        #pragma unroll
        for (int j = 0; j < 8; ++j){
            float v = bf2f(in[j]) * scale1[f0 + j] + shift1[f0 + j];
            o[j] = f2bf(fmaxf(v, 0.f));
        }
        *(ushort4*)(lds + idx*8)     = make_ushort4(o[0], o[1], o[2], o[3]);
        *(ushort4*)(lds + idx*8 + 4) = make_ushort4(o[4], o[5], o[6], o[7]);
    }
    __syncthreads();
    for (int idx = tid; idx < 4704; idx += 256){           // 4 elems each, q = idx*4
        int q = idx * 4;
        int f = q / 196, p0 = q % 196;
        unsigned short o[4];
        #pragma unroll
        for (int j = 0; j < 4; ++j) o[j] = lds[(p0 + j) * 96 + f];
        *(ushort4*)(fcA + (long)b * FLAT + q) = make_ushort4(o[0], o[1], o[2], o[3]);
    }
}

// ---------------------------------------------------------------------------
// fc MFMA: [1024 x 18816] @ [18816 x 208], K split 12-way, atomic fp32 accumulate
__global__ __launch_bounds__(256) void k_fc_mfma(const unsigned short* __restrict__ ab,
                                                 const unsigned short* __restrict__ fcwt,
                                                 float* __restrict__ fc_out){
    const int tid = threadIdx.x, w = tid >> 6, l = tid & 63;
    const int wm = w >> 1, wn = w & 1;
    const int m0 = blockIdx.y * 64 + wm * 32;
    const int n0 = blockIdx.x * 64 + wn * 32;
    const int kb = blockIdx.z * 1568;
    const int lr = l & 15, lk = (l >> 4) * 8;
    f32x4 acc[2][2];
    #pragma unroll
    for (int mi = 0; mi < 2; ++mi)
        #pragma unroll
        for (int nj = 0; nj < 2; ++nj) acc[mi][nj] = (f32x4){0.f, 0.f, 0.f, 0.f};
    for (int k0 = kb; k0 < kb + 1568; k0 += 32){
        bf16x8 a[2], b[2];
        #pragma unroll
        for (int mi = 0; mi < 2; ++mi)
            a[mi] = *(const bf16x8*)(ab + (long)(m0 + mi*16 + lr) * FLAT + k0 + lk);
        #pragma unroll
        for (int nj = 0; nj < 2; ++nj){
            int col = n0 + nj*16 + lr;
            b[nj] = (col < 208) ? *(const bf16x8*)(fcwt + (long)col * FLAT + k0 + lk) : bzero8();
        }
        #pragma unroll
        for (int mi = 0; mi < 2; ++mi)
            #pragma unroll
            for (int nj = 0; nj < 2; ++nj)
                acc[mi][nj] = __builtin_amdgcn_mfma_f32_16x16x32_bf16(a[mi], b[nj], acc[mi][nj], 0, 0, 0);
    }
    #pragma unroll
    for (int mi = 0; mi < 2; ++mi)
        #pragma unroll
        for (int r = 0; r < 4; ++r){
            int row = m0 + mi*16 + (l >> 4) * 4 + r;
            #pragma unroll
            for (int nj = 0; nj < 2; ++nj){
                int col = n0 + nj*16 + lr;
                if (col < 208) atomicAdd(&fc_out[row * 208 + col], acc[mi][nj][r]);
            }
        }
}

__global__ __launch_bounds__(256) void k_bn2_stats(const float* __restrict__ fc_out,
                                                   const float* __restrict__ bn2_g,
                                                   const float* __restrict__ bn2_b,
                                                   float* __restrict__ sc2,
                                                   float* __restrict__ sh2){
    __shared__ float red[8];
    int n = blockIdx.x;
    float s = 0.f, ss = 0.f;
    for (int b = threadIdx.x; b < BATCH; b += 256){
        float v = fc_out[b * 208 + n];
        s += v; ss += v * v;
    }
    block_reduce2(s, ss, red);
    if (threadIdx.x == 0){
        float m = s * (1.f / 1024.f);
        float var = ss * (1.f / 1024.f) - m * m;
        float scv = rsqrtf(var + EPS) * bn2_g[n];
        sc2[n] = scv;
        sh2[n] = bn2_b[n] - m * scv;
    }
}

// A for logits: ab_l[b][k] = bf16(relu(bn2(fc_out))), [1024][224]
__global__ __launch_bounds__(256) void k_prep_logitsA(const float* __restrict__ fc_out,
                                                      const float* __restrict__ sc2,
                                                      const float* __restrict__ sh2,
                                                      unsigned short* __restrict__ ab_l){
    int idx = blockIdx.x * 256 + threadIdx.x;
    if (idx >= BATCH * KP) return;
    int b = idx / KP, k = idx % KP;
    float v = 0.f;
    if (k < D) v = fmaxf(fc_out[b * 208 + k] * sc2[k] + sh2[k], 0.f);
    ab_l[idx] = f2bf(v);
}

// ---------------------------------------------------------------------------
// logits MFMA: [1024 x 224] @ [224 x 50048] -> sigmoid(. + ent_bias) fp32
// Grid: (m fast, n slow) so the 16 m-tiles of one hb n-panel are temporally
// adjacent -> hb panel served from L2/L3 instead of HBM re-fetch per m-pass.
__global__ __launch_bounds__(256) void k_logits_mfma(const unsigned short* __restrict__ ab_l,
                                                     const unsigned short* __restrict__ hb,
                                                     const float* __restrict__ ent_bias,
                                                     float* __restrict__ out){
    const int tid = threadIdx.x, w = tid >> 6, l = tid & 63;
    const int wm = w >> 1, wn = w & 1;
    const int m0 = blockIdx.x * 64 + wm * 32;
    const int n0 = blockIdx.y * 128 + wn * 64;
    const int lr = l & 15, lk = (l >> 4) * 8;
    f32x4 acc[2][4];
    #pragma unroll
    for (int mi = 0; mi < 2; ++mi)
        #pragma unroll
        for (int nj = 0; nj < 4; ++nj) acc[mi][nj] = (f32x4){0.f, 0.f, 0.f, 0.f};
    for (int k0 = 0; k0 < KP; k0 += 32){
        bf16x8 a[2], b[4];
        #pragma unroll
        for (int mi = 0; mi < 2; ++mi)
            a[mi] = *(const bf16x8*)(ab_l + (long)(m0 + mi*16 + lr) * KP + k0 + lk);
        #pragma unroll
        for (int nj = 0; nj < 4; ++nj){
            int cb = n0 + nj*16;
            b[nj] = (cb < N_ENT) ? *(const bf16x8*)(hb + (long)(cb + lr) * KP + k0 + lk) : bzero8();
        }
        #pragma unroll
        for (int mi = 0; mi < 2; ++mi)
            #pragma unroll
            for (int nj = 0; nj < 4; ++nj)
                acc[mi][nj] = __builtin_amdgcn_mfma_f32_16x16x32_bf16(a[mi], b[nj], acc[mi][nj], 0, 0, 0);
    }
    #pragma unroll
    for (int mi = 0; mi < 2; ++mi)
        #pragma unroll
        for (int r = 0; r < 4; ++r){
            int row = m0 + mi*16 + (l >> 4) * 4 + r;
            #pragma unroll
            for (int nj = 0; nj < 4; ++nj){
                int cb = n0 + nj*16;
                if (cb < N_ENT){
                    int col = cb + lr;
                    out[(long)row * N_ENT + col] = sigmoidf(acc[mi][nj][r] + ent_bias[col]);
                }
            }
        }
}

// ---------------------------------------------------------------------------
extern "C" void kernel_launch(void* const* d_in, const int* in_sizes, int n_in,
                              void* d_out, int out_size, void* d_ws, size_t ws_size,
                              hipStream_t stream){
    const float* ent_emb   = (const float*)d_in[0];
    const float* rel_table = (const float*)d_in[1];
    const float* basis     = (const float*)d_in[2];
    const float* att       = (const float*)d_in[3];
    const float* root      = (const float*)d_in[4];
    const float* gbias     = (const float*)d_in[5];
    const float* bn0_g     = (const float*)d_in[6];
    const float* bn0_b     = (const float*)d_in[7];
    const float* conv_k    = (const float*)d_in[8];
    const float* conv_b    = (const float*)d_in[9];
    const float* bn1_g     = (const float*)d_in[10];
    const float* bn1_b     = (const float*)d_in[11];
    const float* fc_W      = (const float*)d_in[12];
    // d_in[13] fc_b cancels through bn2's batch-mean subtraction
    const float* bn2_g     = (const float*)d_in[14];
    const float* bn2_b     = (const float*)d_in[15];
    const float* ent_bias  = (const float*)d_in[16];
    const float* edge_norm = (const float*)d_in[17];
    const int*   entity    = (const int*)d_in[18];
    const int*   edge_index= (const int*)d_in[19];
    const int*   edge_type = (const int*)d_in[20];
    const int*   srcb      = (const int*)d_in[21];
    const int*   relb      = (const int*)d_in[22];
    float* out = (float*)d_out;

    // workspace layout (~160.3 MB). z [0,80M) is dead after k_edge; within it:
    //   hb   [0, 22.42M)          (after edge)
    //   ckb  @22,500,096 (12 KB)  (after edge)
    //   imA  @24M (25.7M)         (after edge; dead after conv gemm)
    //   fcA  @24M (38.5M)         (aliases imA, written after conv gemm)
    //   fcwt @63M (7.8M)          (after edge)
    // h is bf16 [50000][200] = 20 MB @80M.
    char* ws = (char*)d_ws;
    unsigned short* z        = (unsigned short*)(ws);
    unsigned short* hb       = (unsigned short*)(ws);
    unsigned short* ckb      = (unsigned short*)(ws + 22500096);
    unsigned short* imA      = (unsigned short*)(ws + 24000000);
    unsigned short* fcA      = (unsigned short*)(ws + 24000000);
    unsigned short* fcwt     = (unsigned short*)(ws + 63000000);
    unsigned short* h        = (unsigned short*)(ws + 80000000);      // 20,000,000 B (bf16)
    unsigned short* conv_out = (unsigned short*)(ws + 120000000);     // 38,535,168 B
    unsigned short* eb       = (unsigned short*)(ws + 120000000);     // 22,421,504 B (early)
    unsigned short* wb       = (unsigned short*)(ws + 158535168);     //    451,584 B
    float*          fc_out   = (float*)(ws + 158986752);              //    851,968 B
    unsigned short* ab_l     = (unsigned short*)(ws + 159838720);     //    458,752 B
    float*          stats    = (float*)(ws + 160297472);              //      4,096 B
    float* s1sum  = stats + 8;    // [96]
    float* s1ss   = stats + 104;  // [96]
    float* scale1 = stats + 200;  // [96]
    float* shift1 = stats + 296;  // [96]
    float* sc2    = stats + 392;  // [200]
    float* sh2    = stats + 592;  // [200]

    (void)hipMemsetAsync(stats, 0, 4096, stream);
    (void)hipMemsetAsync(fc_out, 0, BATCH * 208 * sizeof(float), stream);

    k_pack_wb      <<<(1008 * KP + 255) / 256, 256, 0, stream>>>(basis, root, wb);
    k_prep_eb      <<<(50048 * 28 + 255) / 256, 256, 0, stream>>>(ent_emb, entity, eb);
    k_gemm_zh_mfma <<<dim3(8, 782), 256, 0, stream>>>(eb, wb, gbias, z, h);
    k_edge         <<<2048, 256, 0, stream>>>(z, h, edge_index, edge_type, edge_norm, att);
    k_bn0_stats    <<<BATCH, 256, 0, stream>>>(h, rel_table, srcb, relb, stats);
    k_h2bf         <<<(50048 * 28 + 255) / 256, 256, 0, stream>>>(h, hb);
    k_pack_fcw     <<<dim3(588, 7), 256, 0, stream>>>(fc_W, fcwt);
    k_pack_ckb     <<<1, 256, 0, stream>>>(conv_k, conv_b, ckb);
    k_im2col       <<<BATCH, 256, 0, stream>>>(h, rel_table, srcb, relb, stats,
                                               bn0_g, bn0_b, imA);
    k_conv_mfma    <<<1568, 256, 0, stream>>>(imA, ckb, conv_out);
    k_bn1_stats2   <<<256, 256, 0, stream>>>(conv_out, s1sum, s1ss);
    k_bn1_final    <<<1, 128, 0, stream>>>(s1sum, s1ss, bn1_g, bn1_b, scale1, shift1);
    k_bn1_tr       <<<BATCH, 256, 0, stream>>>(conv_out, scale1, shift1, fcA);
    k_fc_mfma      <<<dim3(4, 16, 12), 256, 0, stream>>>(fcA, fcwt, fc_out);
    k_bn2_stats    <<<D, 256, 0, stream>>>(fc_out, bn2_g, bn2_b, sc2, sh2);
    k_prep_logitsA <<<(BATCH * KP + 255) / 256, 256, 0, stream>>>(fc_out, sc2, sh2, ab_l);
    k_logits_mfma  <<<dim3(16, 391), 256, 0, stream>>>(ab_l, hb, ent_bias, out);
}